// Round 4
// baseline (482.834 us; speedup 1.0000x reference)
//
#include <hip/hip_runtime.h>
#include <hip/hip_bf16.h>

#define BN 8192
#define LOGB 13

typedef __attribute__((ext_vector_type(8))) short short8;
typedef __attribute__((ext_vector_type(4))) float f32x4;

__device__ __forceinline__ float tanh_fast(float x) {
  x = fminf(fmaxf(x, -15.f), 15.f);
  float t = __expf(2.f * x);
  return (t - 1.f) / (t + 1.f);
}

// native RNE f32->bf16 (compiler emits v_cvt_pk_bf16_f32 for pairs)
__device__ __forceinline__ unsigned short f2bf(float f) {
  union { __hip_bfloat16 h; unsigned short u; } cv;
  cv.h = __float2bfloat16(f);
  return cv.u;
}

__device__ __forceinline__ float bf2f(unsigned short s) {
  return __uint_as_float(((unsigned)s) << 16);
}

// ---- prep: 3 transposes in one kernel ----
__global__ __launch_bounds__(256) void k_prep_tr(
    const float* __restrict__ s0, const float* __restrict__ s1, const float* __restrict__ s2,
    float* __restrict__ d0, float* __restrict__ d1, float* __restrict__ d2) {
  int i = blockIdx.x * 256 + threadIdx.x;
  if (i < 2112) {
    int c = i / 64, r = i - c * 64;
    d0[i] = s0[r * 33 + c];
  } else if (i < 2112 + 8192) {
    int j = i - 2112;
    int c = j / 64, r = j - c * 64;
    d1[j] = s1[r * 128 + c];
  } else if (i < 2112 + 8192 + 2048) {
    int j = i - 2112 - 8192;
    int c = j / 32, r = j - c * 32;
    d2[j] = s2[r * 64 + c];
  }
}

// ---- prep: 7 weight packs in one kernel ----
__device__ __forceinline__ void pack_one(
    const float* __restrict__ W, unsigned short* __restrict__ dst,
    int i, int Nsrc, int Ksrc, int nKs, int skip) {
  int j = i & 7, l = (i >> 3) & 63, fi = i >> 9;
  int ks = fi % nKs, nt = fi / nKs;
  int n = nt * 16 + (l & 15);
  int k = ks * 32 + ((l >> 4) << 3) + j;
  if (skip >= 0 && k >= skip) k++;
  float v = (n < Nsrc && k < Ksrc) ? W[n * Ksrc + k] : 0.f;
  dst[i] = f2bf(v);
}

__global__ __launch_bounds__(256) void k_prep_pack(
    const float* __restrict__ s0, unsigned short* __restrict__ d0,
    const float* __restrict__ s1, unsigned short* __restrict__ d1,
    const float* __restrict__ s2, unsigned short* __restrict__ d2,
    const float* __restrict__ s3, unsigned short* __restrict__ d3,
    const float* __restrict__ s4, unsigned short* __restrict__ d4,
    const float* __restrict__ s5, unsigned short* __restrict__ d5,
    const float* __restrict__ s6, unsigned short* __restrict__ d6) {
  int i = blockIdx.x * 256 + threadIdx.x;
  if (i < 25600) { pack_one(s0, d0, i, 400, 65, 2, 32); return; }
  i -= 25600;
  if (i < 126464) { pack_one(s1, d1, i, 300, 400, 13, -1); return; }
  i -= 126464;
  if (i < 25600) { pack_one(s2, d2, i, 400, 65, 2, 32); return; }
  i -= 25600;
  if (i < 126464) { pack_one(s3, d3, i, 300, 400, 13, -1); return; }
  i -= 126464;
  if (i < 25600) { pack_one(s4, d4, i, 400, 64, 2, -1); return; }
  i -= 25600;
  if (i < 126464) { pack_one(s5, d5, i, 300, 400, 13, -1); return; }
  i -= 126464;
  if (i < 20480) { pack_one(s6, d6, i, 64, 300, 10, -1); return; }
}

// ---------------- fused bottom-up pass: one kernel walks all 15 nodes ----------------
// Block owns 16 batch rows; live child msgs kept in 8 LDS slots (liveness-scheduled).
__global__ __launch_bounds__(256, 2) void k_up_fused(
    const float* __restrict__ x, const float* __restrict__ u,
    const float* __restrict__ w1T, const float* __restrict__ b1,   // [33][64]
    const float* __restrict__ w2T, const float* __restrict__ b2,   // [128][64]
    const float* __restrict__ w3T, const float* __restrict__ b3,   // [64][32]
    float* __restrict__ msg_up) {
  __shared__ float Ms[8][16][32];    // 16384B msg slots
  __shared__ float Xs[16][34];       // 2176B
  __shared__ float Hs[16][128];      // 8192B
  __shared__ float H2s[16][64];      // 4096B   total 30848B
  const int tid = threadIdx.x;
  const int r0 = blockIdx.x * 16;

  // slot schedule: processing order 14..0; node i>=7 -> slot i-7;
  // node6->s6, node5->s4, node4->s2, node3->s0, node2->s4, node1->s0, node0->s0
  const signed char kOut[15] = {0, 0, 4, 0, 2, 4, 6, 0, 1, 2, 3, 4, 5, 6, 7};
  const signed char kChL[7]  = {0, 0, 4, 0, 2, 4, 6};
  const signed char kChR[7]  = {4, 2, 6, 1, 3, 5, 7};

  for (int step = 0; step < 15; step++) {
    const int node = 14 - step;
    const int rbase = (node << LOGB) + r0;
    const bool haveCh = (node < 7);

    for (int f = tid; f < 16 * 33; f += 256) {
      int r = f / 33, c = f - r * 33;
      Xs[r][c] = (c < 32) ? x[(rbase + r) * 32 + c] : u[rbase + r];
    }
    if (haveCh) {
      const int sl = kChL[node], sr = kChR[node];
      for (int f = tid; f < 16 * 64; f += 256) {
        int r = f >> 6, c = f & 63;
        float v = (c < 32) ? Ms[sl][r][c] : Ms[sr][r][c - 32];
        Hs[r][64 + c] = tanh_fast(v);
      }
    }
    __syncthreads();

    const int j = tid & 63, w4 = tid >> 6;
    float acc[4];
#pragma unroll
    for (int i = 0; i < 4; i++) acc[i] = 0.f;
    for (int k = 0; k < 33; k++) {
      float wv = w1T[k * 64 + j];
#pragma unroll
      for (int i = 0; i < 4; i++) acc[i] = fmaf(wv, Xs[w4 * 4 + i][k], acc[i]);
    }
    {
      float bj = b1[j];
#pragma unroll
      for (int i = 0; i < 4; i++) {
        float v = acc[i] + bj;
        float ss = v * v;
#pragma unroll
        for (int off = 32; off; off >>= 1) ss += __shfl_xor(ss, off, 64);
        float inv = 1.f / fmaxf(sqrtf(ss), 1e-12f);
        Hs[w4 * 4 + i][j] = tanh_fast(v * inv);
      }
    }
    __syncthreads();

#pragma unroll
    for (int i = 0; i < 4; i++) acc[i] = 0.f;
    for (int k = 0; k < 64; k++) {
      float wv = w2T[k * 64 + j];
#pragma unroll
      for (int i = 0; i < 4; i++) acc[i] = fmaf(wv, Hs[w4 * 4 + i][k], acc[i]);
    }
    if (haveCh) {   // leaves: children part of Hs is zero -> skip half the K loop
      for (int k = 64; k < 128; k++) {
        float wv = w2T[k * 64 + j];
#pragma unroll
        for (int i = 0; i < 4; i++) acc[i] = fmaf(wv, Hs[w4 * 4 + i][k], acc[i]);
      }
    }
    {
      float b2j = b2[j];
#pragma unroll
      for (int i = 0; i < 4; i++) H2s[w4 * 4 + i][j] = tanh_fast(acc[i] + b2j);
    }
    __syncthreads();

    const int o = tid & 31, rg = tid >> 5;
    float a3[2];
#pragma unroll
    for (int i = 0; i < 2; i++) a3[i] = 0.f;
    for (int k = 0; k < 64; k++) {
      float wv = w3T[k * 32 + o];
#pragma unroll
      for (int i = 0; i < 2; i++) a3[i] = fmaf(wv, H2s[rg * 2 + i][k], a3[i]);
    }
    {
      float b3o = b3[o];
      const int os = kOut[node];
#pragma unroll
      for (int i = 0; i < 2; i++) {
        float v = a3[i] + b3o;
        float ss = v * v;
#pragma unroll
        for (int off = 16; off; off >>= 1) ss += __shfl_xor(ss, off, 32);
        float inv = 1.f / fmaxf(sqrtf(ss), 1e-12f);
        int row = rg * 2 + i;
        float mv = v * inv;
        Ms[os][row][o] = mv;
        msg_up[(rbase + row) * 32 + o] = mv;
      }
    }
    __syncthreads();
  }
}

// ---------------- fused top-down message chain: one kernel walks nodes 0..6 ----------------
// Block owns 32 batch rows; msg_in slots (bf16) in LDS; MFMA layers as before.
__global__ __launch_bounds__(512, 2) void k_mb_fused(
    const float* __restrict__ msg_up,
    const unsigned short* __restrict__ w1f, const unsigned short* __restrict__ w2f,
    const unsigned short* __restrict__ w3f,
    const float* __restrict__ b1, const float* __restrict__ b2, const float* __restrict__ b3,
    float* __restrict__ msg_in_out) {
  __shared__ __align__(16) unsigned short H1s[32 * 424];      // 27136B
  __shared__ __align__(16) unsigned short H2s[32 * 328];      // 20992B
  __shared__ __align__(16) unsigned short MinS[6][32][32];    // 12288B bf16 msg slots
  __shared__ __align__(16) unsigned char XR[32 * 72 * 2];     // 4608B: Xs, overlaid with RedM
  unsigned short* Xs = (unsigned short*)XR;
  float* RedM = (float*)XR;                                    // [4][32], used after Xs dead
  const int tid = threadIdx.x;
  const int r0 = blockIdx.x * 32;
  const int w = tid >> 6, l = tid & 63;
  const int lr = l & 15, lh = l >> 4;

  // zero K-pads once (not overlaid, never clobbered)
  for (int f = tid; f < 32 * 16; f += 512)
    H1s[(f >> 4) * 424 + 400 + (f & 15)] = 0;
  for (int f = tid; f < 32 * 16; f += 512)
    H2s[(f >> 4) * 328 + 304 + (f & 15)] = 0;

  for (int node = 0; node < 7; node++) {
    const int rbase = (node << LOGB) + r0;
    // ---- stage Xs = bf16(tanh(msg_up ‖ msg_in)) ----
    for (int f = tid; f < 32 * 64; f += 512) {
      int r = f >> 6, c = f & 63;
      float v;
      if (c < 32) v = msg_up[(rbase + r) * 32 + c];
      else v = (node > 0) ? bf2f(MinS[node - 1][r][c - 32]) : 0.f;
      Xs[r * 72 + c] = f2bf(tanh_fast(v));
    }
    __syncthreads();

    // ---- layer 1: 25 tiles split (4,3x7) ----
    const int nb1 = (w == 0) ? 0 : (3 * w + 1);
    const int nc1 = (w == 0) ? 4 : 3;
    f32x4 acc1[4][2];
#pragma unroll
    for (int i = 0; i < 4; i++)
#pragma unroll
      for (int m = 0; m < 2; m++) acc1[i][m] = (f32x4)(0.f);
    const short8* w1v = (const short8*)w1f;
#pragma unroll
    for (int ks = 0; ks < 2; ks++) {
      short8 a[2];
#pragma unroll
      for (int m = 0; m < 2; m++)
        a[m] = *(const short8*)&Xs[(m * 16 + lr) * 72 + ks * 32 + lh * 8];
      short8 bfr[4];
#pragma unroll
      for (int nt = 0; nt < 4; nt++)
        if (nt < nc1) bfr[nt] = w1v[((nb1 + nt) * 2 + ks) * 64 + l];
#pragma unroll
      for (int nt = 0; nt < 4; nt++)
        if (nt < nc1)
#pragma unroll
          for (int m = 0; m < 2; m++)
            acc1[nt][m] = __builtin_amdgcn_mfma_f32_16x16x32_bf16(a[m], bfr[nt], acc1[nt][m], 0, 0, 0);
    }
#pragma unroll
    for (int nt = 0; nt < 4; nt++)
      if (nt < nc1) {
        int n = (nb1 + nt) * 16 + lr;
        float bb = b1[n];
#pragma unroll
        for (int m = 0; m < 2; m++)
#pragma unroll
          for (int r = 0; r < 4; r++) {
            float h = fmaxf(acc1[nt][m][r] + bb, 0.f);
            H1s[(m * 16 + lh * 4 + r) * 424 + n] = f2bf(h);
          }
      }
    __syncthreads();

    // ---- layer 2: 19 tiles split (3,3,3,2x5) ----
    const int nb2 = (w < 3) ? 3 * w : (9 + 2 * (w - 3));
    const int nc2 = (w < 3) ? 3 : 2;
    f32x4 acc2[3][2];
#pragma unroll
    for (int i = 0; i < 3; i++)
#pragma unroll
      for (int m = 0; m < 2; m++) acc2[i][m] = (f32x4)(0.f);
    const short8* w2v = (const short8*)w2f;
#pragma unroll 2
    for (int ks = 0; ks < 13; ks++) {
      short8 a[2];
#pragma unroll
      for (int m = 0; m < 2; m++)
        a[m] = *(const short8*)&H1s[(m * 16 + lr) * 424 + ks * 32 + lh * 8];
      short8 bfr[3];
#pragma unroll
      for (int nt = 0; nt < 3; nt++)
        if (nt < nc2) bfr[nt] = w2v[((nb2 + nt) * 13 + ks) * 64 + l];
#pragma unroll
      for (int nt = 0; nt < 3; nt++)
        if (nt < nc2)
#pragma unroll
          for (int m = 0; m < 2; m++)
            acc2[nt][m] = __builtin_amdgcn_mfma_f32_16x16x32_bf16(a[m], bfr[nt], acc2[nt][m], 0, 0, 0);
    }
#pragma unroll
    for (int nt = 0; nt < 3; nt++)
      if (nt < nc2) {
        int n = (nb2 + nt) * 16 + lr;
        float bb = (n < 300) ? b2[n] : 0.f;
#pragma unroll
        for (int m = 0; m < 2; m++)
#pragma unroll
          for (int r = 0; r < 4; r++) {
            float h = (n < 300) ? fmaxf(acc2[nt][m][r] + bb, 0.f) : 0.f;
            H2s[(m * 16 + lh * 4 + r) * 328 + n] = f2bf(h);
          }
      }
    __syncthreads();

    // ---- layer 3: K=320 -> N=64; waves 0..3 own one 16-wide n-tile ----
    f32x4 acc3[2];
#pragma unroll
    for (int m = 0; m < 2; m++) acc3[m] = (f32x4)(0.f);
    float vout[2][4];
    if (w < 4) {
      const short8* w3v = (const short8*)w3f;
#pragma unroll 2
      for (int ks = 0; ks < 10; ks++) {
        short8 a[2];
#pragma unroll
        for (int m = 0; m < 2; m++)
          a[m] = *(const short8*)&H2s[(m * 16 + lr) * 328 + ks * 32 + lh * 8];
        short8 bfr = w3v[(w * 10 + ks) * 64 + l];
#pragma unroll
        for (int m = 0; m < 2; m++)
          acc3[m] = __builtin_amdgcn_mfma_f32_16x16x32_bf16(a[m], bfr, acc3[m], 0, 0, 0);
      }
      float bb = b3[w * 16 + lr];
#pragma unroll
      for (int m = 0; m < 2; m++)
#pragma unroll
        for (int r = 0; r < 4; r++) {
          float v = acc3[m][r] + bb;
          vout[m][r] = v;
          float s = v * v;
          s += __shfl_xor(s, 1, 64);
          s += __shfl_xor(s, 2, 64);
          s += __shfl_xor(s, 4, 64);
          s += __shfl_xor(s, 8, 64);
          if (lr == 0) RedM[w * 32 + m * 16 + lh * 4 + r] = s;
        }
    }
    __syncthreads();
    if (w < 4) {
      const int n3 = w * 16 + lr;
      const int child = 2 * node + 1 + (n3 >> 5);
      const int ccol = n3 & 31;
#pragma unroll
      for (int m = 0; m < 2; m++)
#pragma unroll
        for (int r = 0; r < 4; r++) {
          int row = m * 16 + lh * 4 + r;
          float ss = RedM[0 * 32 + row] + RedM[1 * 32 + row] + RedM[2 * 32 + row] + RedM[3 * 32 + row];
          float inv = 1.f / fmaxf(sqrtf(ss), 1e-12f);
          float mv = vout[m][r] * inv;
          msg_in_out[((child << LOGB) + r0 + row) * 32 + ccol] = mv;
          if (child <= 6) MinS[child - 1][row][ccol] = f2bf(mv);
        }
    }
    __syncthreads();
  }
}

// ---------------- Q nets via MFMA: 512 threads, 64 rows/block, ALL 15 nodes, q1/q2 via blockIdx.y ----
__global__ __launch_bounds__(512, 4) void k_q_mfma(
    const float* __restrict__ msg_up, const float* __restrict__ u,
    const float* __restrict__ msg_in,
    const unsigned short* __restrict__ w1fA, const unsigned short* __restrict__ w2fA,
    const float* __restrict__ w1oA, const float* __restrict__ b1A,
    const float* __restrict__ b2A, const float* __restrict__ w3A, const float* __restrict__ b3A,
    const unsigned short* __restrict__ w1fB, const unsigned short* __restrict__ w2fB,
    const float* __restrict__ w1oB, const float* __restrict__ b1B,
    const float* __restrict__ b2B, const float* __restrict__ w3B, const float* __restrict__ b3B,
    float* __restrict__ out) {
  __shared__ __align__(16) unsigned char sraw[64 * 72 * 2];
  __shared__ __align__(16) unsigned short H1s[64 * 424];
  __shared__ float u_s[64];
  unsigned short* Xs = (unsigned short*)sraw;
  float* Red = (float*)sraw;

  const int tid = threadIdx.x;
  const int net = blockIdx.y;
  const unsigned short* w1f = net ? w1fB : w1fA;
  const unsigned short* w2f = net ? w2fB : w2fA;
  const float* w1o = net ? w1oB : w1oA;
  const float* b1 = net ? b1B : b1A;
  const float* b2 = net ? b2B : b2A;
  const float* w3 = net ? w3B : w3A;
  const float* b3 = net ? b3B : b3A;
  const int r0 = blockIdx.x * 64;
  const int node = r0 >> LOGB;
  const int has_parent = (node > 0);

  for (int f = tid; f < 64 * 64; f += 512) {
    int r = f >> 6, c = f & 63;
    int row = r0 + r;
    float v = (c < 32) ? msg_up[row * 32 + c]
                       : (has_parent ? msg_in[row * 32 + (c - 32)] : 0.f);
    Xs[r * 72 + c] = f2bf(v);
  }
  for (int f = tid; f < 64 * 16; f += 512)
    H1s[(f >> 4) * 424 + 400 + (f & 15)] = 0;
  if (tid < 64) u_s[tid] = u[r0 + tid];
  __syncthreads();

  const int w = tid >> 6, l = tid & 63;
  const int lr = l & 15, lh = l >> 4;

  const int nb1 = (w == 0) ? 0 : (3 * w + 1);
  const int nc1 = (w == 0) ? 4 : 3;
  f32x4 acc1[4][4];
#pragma unroll
  for (int i = 0; i < 4; i++)
#pragma unroll
    for (int m = 0; m < 4; m++) acc1[i][m] = (f32x4)(0.f);
  const short8* w1v = (const short8*)w1f;
#pragma unroll
  for (int ks = 0; ks < 2; ks++) {
    short8 a[4];
#pragma unroll
    for (int m = 0; m < 4; m++)
      a[m] = *(const short8*)&Xs[(m * 16 + lr) * 72 + ks * 32 + lh * 8];
    short8 bfr[4];
#pragma unroll
    for (int nt = 0; nt < 4; nt++)
      if (nt < nc1) bfr[nt] = w1v[((nb1 + nt) * 2 + ks) * 64 + l];
#pragma unroll
    for (int nt = 0; nt < 4; nt++)
      if (nt < nc1)
#pragma unroll
        for (int m = 0; m < 4; m++)
          acc1[nt][m] = __builtin_amdgcn_mfma_f32_16x16x32_bf16(a[m], bfr[nt], acc1[nt][m], 0, 0, 0);
  }
  float uv[4][4];
#pragma unroll
  for (int m = 0; m < 4; m++)
#pragma unroll
    for (int r = 0; r < 4; r++) uv[m][r] = u_s[m * 16 + lh * 4 + r];
#pragma unroll
  for (int nt = 0; nt < 4; nt++)
    if (nt < nc1) {
      int n = (nb1 + nt) * 16 + lr;
      float wu = w1o[n * 65 + 32];
      float bb = b1[n];
#pragma unroll
      for (int m = 0; m < 4; m++)
#pragma unroll
        for (int r = 0; r < 4; r++) {
          float h = acc1[nt][m][r] + uv[m][r] * wu + bb;
          h = fmaxf(h, 0.f);
          H1s[(m * 16 + lh * 4 + r) * 424 + n] = f2bf(h);
        }
    }
  __syncthreads();

  const int nb2 = (w < 3) ? 3 * w : (9 + 2 * (w - 3));
  const int nc2 = (w < 3) ? 3 : 2;
  f32x4 acc2[3][4];
#pragma unroll
  for (int i = 0; i < 3; i++)
#pragma unroll
    for (int m = 0; m < 4; m++) acc2[i][m] = (f32x4)(0.f);
  const short8* w2v = (const short8*)w2f;
#pragma unroll 2
  for (int ks = 0; ks < 13; ks++) {
    short8 a[4];
#pragma unroll
    for (int m = 0; m < 4; m++)
      a[m] = *(const short8*)&H1s[(m * 16 + lr) * 424 + ks * 32 + lh * 8];
    short8 bfr[3];
#pragma unroll
    for (int nt = 0; nt < 3; nt++)
      if (nt < nc2) bfr[nt] = w2v[((nb2 + nt) * 13 + ks) * 64 + l];
#pragma unroll
    for (int nt = 0; nt < 3; nt++)
      if (nt < nc2)
#pragma unroll
        for (int m = 0; m < 4; m++)
          acc2[nt][m] = __builtin_amdgcn_mfma_f32_16x16x32_bf16(a[m], bfr[nt], acc2[nt][m], 0, 0, 0);
  }
  float part[4][4];
#pragma unroll
  for (int m = 0; m < 4; m++)
#pragma unroll
    for (int r = 0; r < 4; r++) part[m][r] = 0.f;
#pragma unroll
  for (int nt = 0; nt < 3; nt++)
    if (nt < nc2) {
      int n = (nb2 + nt) * 16 + lr;
      float bb = (n < 300) ? b2[n] : 0.f;
      float w3n = (n < 300) ? w3[n] : 0.f;
#pragma unroll
      for (int m = 0; m < 4; m++)
#pragma unroll
        for (int r = 0; r < 4; r++) {
          float h = fmaxf(acc2[nt][m][r] + bb, 0.f);
          part[m][r] = fmaf(h, w3n, part[m][r]);
        }
    }
#pragma unroll
  for (int m = 0; m < 4; m++)
#pragma unroll
    for (int r = 0; r < 4; r++) {
      float p = part[m][r];
      p += __shfl_xor(p, 1, 64);
      p += __shfl_xor(p, 2, 64);
      p += __shfl_xor(p, 4, 64);
      p += __shfl_xor(p, 8, 64);
      if (lr == 0) Red[w * 64 + m * 16 + lh * 4 + r] = p;
    }
  __syncthreads();
  if (tid < 64) {
    float q = b3[0];
#pragma unroll
    for (int i = 0; i < 8; i++) q += Red[i * 64 + tid];
    out[(r0 + tid) * 2 + net] = q;
  }
}

extern "C" void kernel_launch(void* const* d_in, const int* in_sizes, int n_in,
                              void* d_out, int out_size, void* d_ws, size_t ws_size,
                              hipStream_t stream) {
  const float* x    = (const float*)d_in[0];
  const float* u    = (const float*)d_in[1];
  const float* up1w = (const float*)d_in[2];  const float* up1b = (const float*)d_in[3];
  const float* up2w = (const float*)d_in[4];  const float* up2b = (const float*)d_in[5];
  const float* up3w = (const float*)d_in[6];  const float* up3b = (const float*)d_in[7];
  const float* q1w1 = (const float*)d_in[8];  const float* q1b1 = (const float*)d_in[9];
  const float* q1w2 = (const float*)d_in[10]; const float* q1b2 = (const float*)d_in[11];
  const float* q1w3 = (const float*)d_in[12]; const float* q1b3 = (const float*)d_in[13];
  const float* q2w1 = (const float*)d_in[14]; const float* q2b1 = (const float*)d_in[15];
  const float* q2w2 = (const float*)d_in[16]; const float* q2b2 = (const float*)d_in[17];
  const float* q2w3 = (const float*)d_in[18]; const float* q2b3 = (const float*)d_in[19];
  const float* mbw1 = (const float*)d_in[20]; const float* mbb1 = (const float*)d_in[21];
  const float* mbw2 = (const float*)d_in[22]; const float* mbb2 = (const float*)d_in[23];
  const float* mbw3 = (const float*)d_in[24]; const float* mbb3 = (const float*)d_in[25];
  float* out = (float*)d_out;
  float* ws  = (float*)d_ws;

  float* msg_up = ws;                        // 15*8192*32
  float* msg_in = msg_up + 15 * BN * 32;     // 15*8192*32
  float* t_up1  = msg_in + 15 * BN * 32;     // [33][64]
  float* t_up2  = t_up1 + 33 * 64;           // [128][64]
  float* t_up3  = t_up2 + 128 * 64;          // [64][32]
  unsigned short* frag = (unsigned short*)(t_up3 + 64 * 32);
  unsigned short* q1w1f = frag;              // 25*2*512  = 25600
  unsigned short* q1w2f = q1w1f + 25600;     // 19*13*512 = 126464
  unsigned short* q2w1f = q1w2f + 126464;
  unsigned short* q2w2f = q2w1f + 25600;
  unsigned short* mbw1f = q2w2f + 126464;
  unsigned short* mbw2f = mbw1f + 25600;
  unsigned short* mbw3f = mbw2f + 126464;    // 4*10*512 = 20480

  k_prep_tr<<<dim3((12352 + 255) / 256), dim3(256), 0, stream>>>(
      up1w, up2w, up3w, t_up1, t_up2, t_up3);
  k_prep_pack<<<dim3((476672 + 255) / 256), dim3(256), 0, stream>>>(
      q1w1, q1w1f, q1w2, q1w2f, q2w1, q2w1f, q2w2, q2w2f,
      mbw1, mbw1f, mbw2, mbw2f, mbw3, mbw3f);

  // ---- fused bottom-up: one launch ----
  k_up_fused<<<dim3(BN / 16), dim3(256), 0, stream>>>(
      x, u, t_up1, up1b, t_up2, up2b, t_up3, up3b, msg_up);

  // ---- fused message chain: one launch ----
  k_mb_fused<<<dim3(BN / 32), dim3(512), 0, stream>>>(
      msg_up, mbw1f, mbw2f, mbw3f, mbb1, mbb2, mbb3, msg_in);

  // ---- Q: one launch over all 15 nodes, both nets ----
  k_q_mfma<<<dim3(15 * (BN / 64), 2), dim3(512), 0, stream>>>(
      msg_up, u, msg_in,
      q1w1f, q1w2f, q1w1, q1b1, q1b2, q1w3, q1b3,
      q2w1f, q2w2f, q2w1, q2b1, q2b2, q2w3, q2b3,
      out);
}

// Round 5
// 319.794 us; speedup vs baseline: 1.5098x; 1.5098x over previous
//
#include <hip/hip_runtime.h>
#include <hip/hip_bf16.h>

#define BN 8192
#define LOGB 13

typedef __attribute__((ext_vector_type(8))) short short8;
typedef __attribute__((ext_vector_type(4))) float f32x4;

__device__ __forceinline__ float tanh_fast(float x) {
  x = fminf(fmaxf(x, -15.f), 15.f);
  float t = __expf(2.f * x);
  return (t - 1.f) / (t + 1.f);
}

__device__ __forceinline__ unsigned short f2bf(float f) {
  union { __hip_bfloat16 h; unsigned short u; } cv;
  cv.h = __float2bfloat16(f);
  return cv.u;
}

__device__ __forceinline__ float bf2f(unsigned short s) {
  return __uint_as_float(((unsigned)s) << 16);
}

// ---- prep: 3 transposes in one kernel ----
__global__ __launch_bounds__(256) void k_prep_tr(
    const float* __restrict__ s0, const float* __restrict__ s1, const float* __restrict__ s2,
    float* __restrict__ d0, float* __restrict__ d1, float* __restrict__ d2) {
  int i = blockIdx.x * 256 + threadIdx.x;
  if (i < 2112) {
    int c = i / 64, r = i - c * 64;
    d0[i] = s0[r * 33 + c];
  } else if (i < 2112 + 8192) {
    int j = i - 2112;
    int c = j / 64, r = j - c * 64;
    d1[j] = s1[r * 128 + c];
  } else if (i < 2112 + 8192 + 2048) {
    int j = i - 2112 - 8192;
    int c = j / 32, r = j - c * 32;
    d2[j] = s2[r * 64 + c];
  }
}

// ---- prep: 7 weight packs in one kernel ----
__device__ __forceinline__ void pack_one(
    const float* __restrict__ W, unsigned short* __restrict__ dst,
    int i, int Nsrc, int Ksrc, int nKs, int skip) {
  int j = i & 7, l = (i >> 3) & 63, fi = i >> 9;
  int ks = fi % nKs, nt = fi / nKs;
  int n = nt * 16 + (l & 15);
  int k = ks * 32 + ((l >> 4) << 3) + j;
  if (skip >= 0 && k >= skip) k++;
  float v = (n < Nsrc && k < Ksrc) ? W[n * Ksrc + k] : 0.f;
  dst[i] = f2bf(v);
}

__global__ __launch_bounds__(256) void k_prep_pack(
    const float* __restrict__ s0, unsigned short* __restrict__ d0,
    const float* __restrict__ s1, unsigned short* __restrict__ d1,
    const float* __restrict__ s2, unsigned short* __restrict__ d2,
    const float* __restrict__ s3, unsigned short* __restrict__ d3,
    const float* __restrict__ s4, unsigned short* __restrict__ d4,
    const float* __restrict__ s5, unsigned short* __restrict__ d5,
    const float* __restrict__ s6, unsigned short* __restrict__ d6) {
  int i = blockIdx.x * 256 + threadIdx.x;
  if (i < 25600) { pack_one(s0, d0, i, 400, 65, 2, 32); return; }
  i -= 25600;
  if (i < 126464) { pack_one(s1, d1, i, 300, 400, 13, -1); return; }
  i -= 126464;
  if (i < 25600) { pack_one(s2, d2, i, 400, 65, 2, 32); return; }
  i -= 25600;
  if (i < 126464) { pack_one(s3, d3, i, 300, 400, 13, -1); return; }
  i -= 126464;
  if (i < 25600) { pack_one(s4, d4, i, 400, 64, 2, -1); return; }
  i -= 25600;
  if (i < 126464) { pack_one(s5, d5, i, 300, 400, 13, -1); return; }
  i -= 126464;
  if (i < 20480) { pack_one(s6, d6, i, 64, 300, 10, -1); return; }
}

// ---------------- fused bottom-up pass: weights LDS-resident (bf16) ----------------
__global__ __launch_bounds__(256, 2) void k_up_fused(
    const float* __restrict__ x, const float* __restrict__ u,
    const float* __restrict__ w1T, const float* __restrict__ b1,   // [33][64] fp32
    const float* __restrict__ w2T, const float* __restrict__ b2,   // [128][64]
    const float* __restrict__ w3T, const float* __restrict__ b3,   // [64][32]
    float* __restrict__ msg_up) {
  __shared__ float Ms[8][16][32];          // 16384B msg slots (fp32 for chain accuracy)
  __shared__ float Xs[16][34];             // 2176B
  __shared__ float Hs[16][128];            // 8192B
  __shared__ float H2s[16][64];            // 4096B
  __shared__ unsigned short W1s[33 * 64];  // 4224B
  __shared__ unsigned short W2s[128 * 64]; // 16384B
  __shared__ unsigned short W3s[64 * 32];  // 4096B
  __shared__ float B1s[64], B2s[64], B3s[32];  // 640B  -> total ~55.9KB
  const int tid = threadIdx.x;
  const int r0 = blockIdx.x * 16;

  // ---- stage weights once per block ----
  for (int i = tid; i < 33 * 64; i += 256) W1s[i] = f2bf(w1T[i]);
  for (int i = tid; i < 128 * 64; i += 256) W2s[i] = f2bf(w2T[i]);
  for (int i = tid; i < 64 * 32; i += 256) W3s[i] = f2bf(w3T[i]);
  if (tid < 64) { B1s[tid] = b1[tid]; B2s[tid] = b2[tid]; }
  else if (tid < 96) B3s[tid - 64] = b3[tid - 64];

  // slot schedule: processing order 14..0; node i>=7 -> slot i-7;
  const signed char kOut[15] = {0, 0, 4, 0, 2, 4, 6, 0, 1, 2, 3, 4, 5, 6, 7};
  const signed char kChL[7]  = {0, 0, 4, 0, 2, 4, 6};
  const signed char kChR[7]  = {4, 2, 6, 1, 3, 5, 7};

  for (int step = 0; step < 15; step++) {
    const int node = 14 - step;
    const int rbase = (node << LOGB) + r0;
    const bool haveCh = (node < 7);

    for (int f = tid; f < 16 * 33; f += 256) {
      int r = f / 33, c = f - r * 33;
      Xs[r][c] = (c < 32) ? x[(rbase + r) * 32 + c] : u[rbase + r];
    }
    if (haveCh) {
      const int sl = kChL[node], sr = kChR[node];
      for (int f = tid; f < 16 * 64; f += 256) {
        int r = f >> 6, c = f & 63;
        float v = (c < 32) ? Ms[sl][r][c] : Ms[sr][r][c - 32];
        Hs[r][64 + c] = tanh_fast(v);
      }
    }
    __syncthreads();

    const int j = tid & 63, w4 = tid >> 6;
    float acc[4];
#pragma unroll
    for (int i = 0; i < 4; i++) acc[i] = 0.f;
    for (int k = 0; k < 33; k++) {
      float wv = bf2f(W1s[k * 64 + j]);
#pragma unroll
      for (int i = 0; i < 4; i++) acc[i] = fmaf(wv, Xs[w4 * 4 + i][k], acc[i]);
    }
    {
      float bj = B1s[j];
#pragma unroll
      for (int i = 0; i < 4; i++) {
        float v = acc[i] + bj;
        float ss = v * v;
#pragma unroll
        for (int off = 32; off; off >>= 1) ss += __shfl_xor(ss, off, 64);
        float inv = 1.f / fmaxf(sqrtf(ss), 1e-12f);
        Hs[w4 * 4 + i][j] = tanh_fast(v * inv);
      }
    }
    __syncthreads();

#pragma unroll
    for (int i = 0; i < 4; i++) acc[i] = 0.f;
    for (int k = 0; k < 64; k++) {
      float wv = bf2f(W2s[k * 64 + j]);
#pragma unroll
      for (int i = 0; i < 4; i++) acc[i] = fmaf(wv, Hs[w4 * 4 + i][k], acc[i]);
    }
    if (haveCh) {   // leaves: children half of Hs is tanh(0)=0 -> skip
      for (int k = 64; k < 128; k++) {
        float wv = bf2f(W2s[k * 64 + j]);
#pragma unroll
        for (int i = 0; i < 4; i++) acc[i] = fmaf(wv, Hs[w4 * 4 + i][k], acc[i]);
      }
    }
    {
      float b2j = B2s[j];
#pragma unroll
      for (int i = 0; i < 4; i++) H2s[w4 * 4 + i][j] = tanh_fast(acc[i] + b2j);
    }
    __syncthreads();

    const int o = tid & 31, rg = tid >> 5;
    float a3[2];
#pragma unroll
    for (int i = 0; i < 2; i++) a3[i] = 0.f;
    for (int k = 0; k < 64; k++) {
      float wv = bf2f(W3s[k * 32 + o]);
#pragma unroll
      for (int i = 0; i < 2; i++) a3[i] = fmaf(wv, H2s[rg * 2 + i][k], a3[i]);
    }
    {
      float b3o = B3s[o];
      const int os = kOut[node];
#pragma unroll
      for (int i = 0; i < 2; i++) {
        float v = a3[i] + b3o;
        float ss = v * v;
#pragma unroll
        for (int off = 16; off; off >>= 1) ss += __shfl_xor(ss, off, 32);
        float inv = 1.f / fmaxf(sqrtf(ss), 1e-12f);
        int row = rg * 2 + i;
        float mv = v * inv;
        Ms[os][row][o] = mv;
        msg_up[(rbase + row) * 32 + o] = mv;
      }
    }
    __syncthreads();
  }
}

// ---------------- fused top-down message chain: one kernel walks nodes 0..6 ----------------
__global__ __launch_bounds__(512, 2) void k_mb_fused(
    const float* __restrict__ msg_up,
    const unsigned short* __restrict__ w1f, const unsigned short* __restrict__ w2f,
    const unsigned short* __restrict__ w3f,
    const float* __restrict__ b1, const float* __restrict__ b2, const float* __restrict__ b3,
    float* __restrict__ msg_in_out) {
  __shared__ __align__(16) unsigned short H1s[32 * 424];      // 27136B
  __shared__ __align__(16) unsigned short H2s[32 * 328];      // 20992B
  __shared__ __align__(16) unsigned short MinS[6][32][32];    // 12288B bf16 msg slots
  __shared__ __align__(16) unsigned char XR[32 * 72 * 2];     // 4608B: Xs, overlaid with RedM
  unsigned short* Xs = (unsigned short*)XR;
  float* RedM = (float*)XR;
  const int tid = threadIdx.x;
  const int r0 = blockIdx.x * 32;
  const int w = tid >> 6, l = tid & 63;
  const int lr = l & 15, lh = l >> 4;

  for (int f = tid; f < 32 * 16; f += 512)
    H1s[(f >> 4) * 424 + 400 + (f & 15)] = 0;
  for (int f = tid; f < 32 * 16; f += 512)
    H2s[(f >> 4) * 328 + 304 + (f & 15)] = 0;

  for (int node = 0; node < 7; node++) {
    const int rbase = (node << LOGB) + r0;
    for (int f = tid; f < 32 * 64; f += 512) {
      int r = f >> 6, c = f & 63;
      float v;
      if (c < 32) v = msg_up[(rbase + r) * 32 + c];
      else v = (node > 0) ? bf2f(MinS[node - 1][r][c - 32]) : 0.f;
      Xs[r * 72 + c] = f2bf(tanh_fast(v));
    }
    __syncthreads();

    const int nb1 = (w == 0) ? 0 : (3 * w + 1);
    const int nc1 = (w == 0) ? 4 : 3;
    f32x4 acc1[4][2];
#pragma unroll
    for (int i = 0; i < 4; i++)
#pragma unroll
      for (int m = 0; m < 2; m++) acc1[i][m] = (f32x4)(0.f);
    const short8* w1v = (const short8*)w1f;
#pragma unroll
    for (int ks = 0; ks < 2; ks++) {
      short8 a[2];
#pragma unroll
      for (int m = 0; m < 2; m++)
        a[m] = *(const short8*)&Xs[(m * 16 + lr) * 72 + ks * 32 + lh * 8];
      short8 bfr[4];
#pragma unroll
      for (int nt = 0; nt < 4; nt++)
        if (nt < nc1) bfr[nt] = w1v[((nb1 + nt) * 2 + ks) * 64 + l];
#pragma unroll
      for (int nt = 0; nt < 4; nt++)
        if (nt < nc1)
#pragma unroll
          for (int m = 0; m < 2; m++)
            acc1[nt][m] = __builtin_amdgcn_mfma_f32_16x16x32_bf16(a[m], bfr[nt], acc1[nt][m], 0, 0, 0);
    }
#pragma unroll
    for (int nt = 0; nt < 4; nt++)
      if (nt < nc1) {
        int n = (nb1 + nt) * 16 + lr;
        float bb = b1[n];
#pragma unroll
        for (int m = 0; m < 2; m++)
#pragma unroll
          for (int r = 0; r < 4; r++) {
            float h = fmaxf(acc1[nt][m][r] + bb, 0.f);
            H1s[(m * 16 + lh * 4 + r) * 424 + n] = f2bf(h);
          }
      }
    __syncthreads();

    const int nb2 = (w < 3) ? 3 * w : (9 + 2 * (w - 3));
    const int nc2 = (w < 3) ? 3 : 2;
    f32x4 acc2[3][2];
#pragma unroll
    for (int i = 0; i < 3; i++)
#pragma unroll
      for (int m = 0; m < 2; m++) acc2[i][m] = (f32x4)(0.f);
    const short8* w2v = (const short8*)w2f;
#pragma unroll 2
    for (int ks = 0; ks < 13; ks++) {
      short8 a[2];
#pragma unroll
      for (int m = 0; m < 2; m++)
        a[m] = *(const short8*)&H1s[(m * 16 + lr) * 424 + ks * 32 + lh * 8];
      short8 bfr[3];
#pragma unroll
      for (int nt = 0; nt < 3; nt++)
        if (nt < nc2) bfr[nt] = w2v[((nb2 + nt) * 13 + ks) * 64 + l];
#pragma unroll
      for (int nt = 0; nt < 3; nt++)
        if (nt < nc2)
#pragma unroll
          for (int m = 0; m < 2; m++)
            acc2[nt][m] = __builtin_amdgcn_mfma_f32_16x16x32_bf16(a[m], bfr[nt], acc2[nt][m], 0, 0, 0);
    }
#pragma unroll
    for (int nt = 0; nt < 3; nt++)
      if (nt < nc2) {
        int n = (nb2 + nt) * 16 + lr;
        float bb = (n < 300) ? b2[n] : 0.f;
#pragma unroll
        for (int m = 0; m < 2; m++)
#pragma unroll
          for (int r = 0; r < 4; r++) {
            float h = (n < 300) ? fmaxf(acc2[nt][m][r] + bb, 0.f) : 0.f;
            H2s[(m * 16 + lh * 4 + r) * 328 + n] = f2bf(h);
          }
      }
    __syncthreads();

    f32x4 acc3[2];
#pragma unroll
    for (int m = 0; m < 2; m++) acc3[m] = (f32x4)(0.f);
    float vout[2][4];
    if (w < 4) {
      const short8* w3v = (const short8*)w3f;
#pragma unroll 2
      for (int ks = 0; ks < 10; ks++) {
        short8 a[2];
#pragma unroll
        for (int m = 0; m < 2; m++)
          a[m] = *(const short8*)&H2s[(m * 16 + lr) * 328 + ks * 32 + lh * 8];
        short8 bfr = w3v[(w * 10 + ks) * 64 + l];
#pragma unroll
        for (int m = 0; m < 2; m++)
          acc3[m] = __builtin_amdgcn_mfma_f32_16x16x32_bf16(a[m], bfr, acc3[m], 0, 0, 0);
      }
      float bb = b3[w * 16 + lr];
#pragma unroll
      for (int m = 0; m < 2; m++)
#pragma unroll
        for (int r = 0; r < 4; r++) {
          float v = acc3[m][r] + bb;
          vout[m][r] = v;
          float s = v * v;
          s += __shfl_xor(s, 1, 64);
          s += __shfl_xor(s, 2, 64);
          s += __shfl_xor(s, 4, 64);
          s += __shfl_xor(s, 8, 64);
          if (lr == 0) RedM[w * 32 + m * 16 + lh * 4 + r] = s;
        }
    }
    __syncthreads();
    if (w < 4) {
      const int n3 = w * 16 + lr;
      const int child = 2 * node + 1 + (n3 >> 5);
      const int ccol = n3 & 31;
#pragma unroll
      for (int m = 0; m < 2; m++)
#pragma unroll
        for (int r = 0; r < 4; r++) {
          int row = m * 16 + lh * 4 + r;
          float ss = RedM[0 * 32 + row] + RedM[1 * 32 + row] + RedM[2 * 32 + row] + RedM[3 * 32 + row];
          float inv = 1.f / fmaxf(sqrtf(ss), 1e-12f);
          float mv = vout[m][r] * inv;
          msg_in_out[((child << LOGB) + r0 + row) * 32 + ccol] = mv;
          if (child <= 6) MinS[child - 1][row][ccol] = f2bf(mv);
        }
    }
    __syncthreads();
  }
}

// ---------------- Q nets via MFMA: 512 threads, 64 rows/block, ALL 15 nodes, q1/q2 via blockIdx.y ----
__global__ __launch_bounds__(512, 4) void k_q_mfma(
    const float* __restrict__ msg_up, const float* __restrict__ u,
    const float* __restrict__ msg_in,
    const unsigned short* __restrict__ w1fA, const unsigned short* __restrict__ w2fA,
    const float* __restrict__ w1oA, const float* __restrict__ b1A,
    const float* __restrict__ b2A, const float* __restrict__ w3A, const float* __restrict__ b3A,
    const unsigned short* __restrict__ w1fB, const unsigned short* __restrict__ w2fB,
    const float* __restrict__ w1oB, const float* __restrict__ b1B,
    const float* __restrict__ b2B, const float* __restrict__ w3B, const float* __restrict__ b3B,
    float* __restrict__ out) {
  __shared__ __align__(16) unsigned char sraw[64 * 72 * 2];
  __shared__ __align__(16) unsigned short H1s[64 * 424];
  __shared__ float u_s[64];
  unsigned short* Xs = (unsigned short*)sraw;
  float* Red = (float*)sraw;

  const int tid = threadIdx.x;
  const int net = blockIdx.y;
  const unsigned short* w1f = net ? w1fB : w1fA;
  const unsigned short* w2f = net ? w2fB : w2fA;
  const float* w1o = net ? w1oB : w1oA;
  const float* b1 = net ? b1B : b1A;
  const float* b2 = net ? b2B : b2A;
  const float* w3 = net ? w3B : w3A;
  const float* b3 = net ? b3B : b3A;
  const int r0 = blockIdx.x * 64;
  const int node = r0 >> LOGB;
  const int has_parent = (node > 0);

  for (int f = tid; f < 64 * 64; f += 512) {
    int r = f >> 6, c = f & 63;
    int row = r0 + r;
    float v = (c < 32) ? msg_up[row * 32 + c]
                       : (has_parent ? msg_in[row * 32 + (c - 32)] : 0.f);
    Xs[r * 72 + c] = f2bf(v);
  }
  for (int f = tid; f < 64 * 16; f += 512)
    H1s[(f >> 4) * 424 + 400 + (f & 15)] = 0;
  if (tid < 64) u_s[tid] = u[r0 + tid];
  __syncthreads();

  const int w = tid >> 6, l = tid & 63;
  const int lr = l & 15, lh = l >> 4;

  const int nb1 = (w == 0) ? 0 : (3 * w + 1);
  const int nc1 = (w == 0) ? 4 : 3;
  f32x4 acc1[4][4];
#pragma unroll
  for (int i = 0; i < 4; i++)
#pragma unroll
    for (int m = 0; m < 4; m++) acc1[i][m] = (f32x4)(0.f);
  const short8* w1v = (const short8*)w1f;
#pragma unroll
  for (int ks = 0; ks < 2; ks++) {
    short8 a[4];
#pragma unroll
    for (int m = 0; m < 4; m++)
      a[m] = *(const short8*)&Xs[(m * 16 + lr) * 72 + ks * 32 + lh * 8];
    short8 bfr[4];
#pragma unroll
    for (int nt = 0; nt < 4; nt++)
      if (nt < nc1) bfr[nt] = w1v[((nb1 + nt) * 2 + ks) * 64 + l];
#pragma unroll
    for (int nt = 0; nt < 4; nt++)
      if (nt < nc1)
#pragma unroll
        for (int m = 0; m < 4; m++)
          acc1[nt][m] = __builtin_amdgcn_mfma_f32_16x16x32_bf16(a[m], bfr[nt], acc1[nt][m], 0, 0, 0);
  }
  float uv[4][4];
#pragma unroll
  for (int m = 0; m < 4; m++)
#pragma unroll
    for (int r = 0; r < 4; r++) uv[m][r] = u_s[m * 16 + lh * 4 + r];
#pragma unroll
  for (int nt = 0; nt < 4; nt++)
    if (nt < nc1) {
      int n = (nb1 + nt) * 16 + lr;
      float wu = w1o[n * 65 + 32];
      float bb = b1[n];
#pragma unroll
      for (int m = 0; m < 4; m++)
#pragma unroll
        for (int r = 0; r < 4; r++) {
          float h = acc1[nt][m][r] + uv[m][r] * wu + bb;
          h = fmaxf(h, 0.f);
          H1s[(m * 16 + lh * 4 + r) * 424 + n] = f2bf(h);
        }
    }
  __syncthreads();

  const int nb2 = (w < 3) ? 3 * w : (9 + 2 * (w - 3));
  const int nc2 = (w < 3) ? 3 : 2;
  f32x4 acc2[3][4];
#pragma unroll
  for (int i = 0; i < 3; i++)
#pragma unroll
    for (int m = 0; m < 4; m++) acc2[i][m] = (f32x4)(0.f);
  const short8* w2v = (const short8*)w2f;
#pragma unroll 2
  for (int ks = 0; ks < 13; ks++) {
    short8 a[4];
#pragma unroll
    for (int m = 0; m < 4; m++)
      a[m] = *(const short8*)&H1s[(m * 16 + lr) * 424 + ks * 32 + lh * 8];
    short8 bfr[3];
#pragma unroll
    for (int nt = 0; nt < 3; nt++)
      if (nt < nc2) bfr[nt] = w2v[((nb2 + nt) * 13 + ks) * 64 + l];
#pragma unroll
    for (int nt = 0; nt < 3; nt++)
      if (nt < nc2)
#pragma unroll
        for (int m = 0; m < 4; m++)
          acc2[nt][m] = __builtin_amdgcn_mfma_f32_16x16x32_bf16(a[m], bfr[nt], acc2[nt][m], 0, 0, 0);
  }
  float part[4][4];
#pragma unroll
  for (int m = 0; m < 4; m++)
#pragma unroll
    for (int r = 0; r < 4; r++) part[m][r] = 0.f;
#pragma unroll
  for (int nt = 0; nt < 3; nt++)
    if (nt < nc2) {
      int n = (nb2 + nt) * 16 + lr;
      float bb = (n < 300) ? b2[n] : 0.f;
      float w3n = (n < 300) ? w3[n] : 0.f;
#pragma unroll
      for (int m = 0; m < 4; m++)
#pragma unroll
        for (int r = 0; r < 4; r++) {
          float h = fmaxf(acc2[nt][m][r] + bb, 0.f);
          part[m][r] = fmaf(h, w3n, part[m][r]);
        }
    }
#pragma unroll
  for (int m = 0; m < 4; m++)
#pragma unroll
    for (int r = 0; r < 4; r++) {
      float p = part[m][r];
      p += __shfl_xor(p, 1, 64);
      p += __shfl_xor(p, 2, 64);
      p += __shfl_xor(p, 4, 64);
      p += __shfl_xor(p, 8, 64);
      if (lr == 0) Red[w * 64 + m * 16 + lh * 4 + r] = p;
    }
  __syncthreads();
  if (tid < 64) {
    float q = b3[0];
#pragma unroll
    for (int i = 0; i < 8; i++) q += Red[i * 64 + tid];
    out[(r0 + tid) * 2 + net] = q;
  }
}

extern "C" void kernel_launch(void* const* d_in, const int* in_sizes, int n_in,
                              void* d_out, int out_size, void* d_ws, size_t ws_size,
                              hipStream_t stream) {
  const float* x    = (const float*)d_in[0];
  const float* u    = (const float*)d_in[1];
  const float* up1w = (const float*)d_in[2];  const float* up1b = (const float*)d_in[3];
  const float* up2w = (const float*)d_in[4];  const float* up2b = (const float*)d_in[5];
  const float* up3w = (const float*)d_in[6];  const float* up3b = (const float*)d_in[7];
  const float* q1w1 = (const float*)d_in[8];  const float* q1b1 = (const float*)d_in[9];
  const float* q1w2 = (const float*)d_in[10]; const float* q1b2 = (const float*)d_in[11];
  const float* q1w3 = (const float*)d_in[12]; const float* q1b3 = (const float*)d_in[13];
  const float* q2w1 = (const float*)d_in[14]; const float* q2b1 = (const float*)d_in[15];
  const float* q2w2 = (const float*)d_in[16]; const float* q2b2 = (const float*)d_in[17];
  const float* q2w3 = (const float*)d_in[18]; const float* q2b3 = (const float*)d_in[19];
  const float* mbw1 = (const float*)d_in[20]; const float* mbb1 = (const float*)d_in[21];
  const float* mbw2 = (const float*)d_in[22]; const float* mbb2 = (const float*)d_in[23];
  const float* mbw3 = (const float*)d_in[24]; const float* mbb3 = (const float*)d_in[25];
  float* out = (float*)d_out;
  float* ws  = (float*)d_ws;

  float* msg_up = ws;                        // 15*8192*32
  float* msg_in = msg_up + 15 * BN * 32;     // 15*8192*32
  float* t_up1  = msg_in + 15 * BN * 32;     // [33][64]
  float* t_up2  = t_up1 + 33 * 64;           // [128][64]
  float* t_up3  = t_up2 + 128 * 64;          // [64][32]
  unsigned short* frag = (unsigned short*)(t_up3 + 64 * 32);
  unsigned short* q1w1f = frag;              // 25*2*512  = 25600
  unsigned short* q1w2f = q1w1f + 25600;     // 19*13*512 = 126464
  unsigned short* q2w1f = q1w2f + 126464;
  unsigned short* q2w2f = q2w1f + 25600;
  unsigned short* mbw1f = q2w2f + 126464;
  unsigned short* mbw2f = mbw1f + 25600;
  unsigned short* mbw3f = mbw2f + 126464;    // 4*10*512 = 20480

  k_prep_tr<<<dim3((12352 + 255) / 256), dim3(256), 0, stream>>>(
      up1w, up2w, up3w, t_up1, t_up2, t_up3);
  k_prep_pack<<<dim3((476672 + 255) / 256), dim3(256), 0, stream>>>(
      q1w1, q1w1f, q1w2, q1w2f, q2w1, q2w1f, q2w2, q2w2f,
      mbw1, mbw1f, mbw2, mbw2f, mbw3, mbw3f);

  // ---- fused bottom-up: one launch, weights LDS-resident ----
  k_up_fused<<<dim3(BN / 16), dim3(256), 0, stream>>>(
      x, u, t_up1, up1b, t_up2, up2b, t_up3, up3b, msg_up);

  // ---- fused message chain: one launch ----
  k_mb_fused<<<dim3(BN / 32), dim3(512), 0, stream>>>(
      msg_up, mbw1f, mbw2f, mbw3f, mbb1, mbb2, mbb3, msg_in);

  // ---- Q: one launch over all 15 nodes, both nets ----
  k_q_mfma<<<dim3(15 * (BN / 64), 2), dim3(512), 0, stream>>>(
      msg_up, u, msg_in,
      q1w1f, q1w2f, q1w1, q1b1, q1b2, q1w3, q1b3,
      q2w1f, q2w2f, q2w1, q2b1, q2b2, q2w3, q2b3,
      out);
}

// Round 6
// 237.478 us; speedup vs baseline: 2.0332x; 1.3466x over previous
//
#include <hip/hip_runtime.h>
#include <hip/hip_bf16.h>

#define BN 8192
#define LOGB 13

typedef __attribute__((ext_vector_type(8))) short short8;
typedef __attribute__((ext_vector_type(4))) float f32x4;

__device__ __forceinline__ float tanh_fast(float x) {
  x = fminf(fmaxf(x, -15.f), 15.f);
  float t = __expf(2.f * x);
  return (t - 1.f) / (t + 1.f);
}

__device__ __forceinline__ unsigned short f2bf(float f) {
  union { __hip_bfloat16 h; unsigned short u; } cv;
  cv.h = __float2bfloat16(f);
  return cv.u;
}

__device__ __forceinline__ float bf2f(unsigned short s) {
  return __uint_as_float(((unsigned)s) << 16);
}

// ---- prep: 10 weight packs in one kernel ----
// pack: dst[((nt*nKs+ks)*64+l)*8+j] = W[nt*16+(l&15)][kmap(ks*32+(l>>4)*8+j)]
__device__ __forceinline__ void pack_one(
    const float* __restrict__ W, unsigned short* __restrict__ dst,
    int i, int Nsrc, int Ksrc, int nKs, int skip) {
  int j = i & 7, l = (i >> 3) & 63, fi = i >> 9;
  int ks = fi % nKs, nt = fi / nKs;
  int n = nt * 16 + (l & 15);
  int k = ks * 32 + ((l >> 4) << 3) + j;
  if (skip >= 0 && k >= skip) k++;
  float v = (n < Nsrc && k < Ksrc) ? W[n * Ksrc + k] : 0.f;
  dst[i] = f2bf(v);
}

__global__ __launch_bounds__(256) void k_prep_pack(
    const float* __restrict__ s0, unsigned short* __restrict__ d0,   // q1w1 400x65
    const float* __restrict__ s1, unsigned short* __restrict__ d1,   // q1w2 300x400
    const float* __restrict__ s2, unsigned short* __restrict__ d2,   // q2w1
    const float* __restrict__ s3, unsigned short* __restrict__ d3,   // q2w2
    const float* __restrict__ s4, unsigned short* __restrict__ d4,   // mbw1 400x64
    const float* __restrict__ s5, unsigned short* __restrict__ d5,   // mbw2 300x400
    const float* __restrict__ s6, unsigned short* __restrict__ d6,   // mbw3 64x300
    const float* __restrict__ s7, unsigned short* __restrict__ d7,   // up1w 64x33 (K=32)
    const float* __restrict__ s8, unsigned short* __restrict__ d8,   // up2w 64x128
    const float* __restrict__ s9, unsigned short* __restrict__ d9) { // up3w 32x64
  int i = blockIdx.x * 256 + threadIdx.x;
  if (i < 25600) { pack_one(s0, d0, i, 400, 65, 2, 32); return; }
  i -= 25600;
  if (i < 126464) { pack_one(s1, d1, i, 300, 400, 13, -1); return; }
  i -= 126464;
  if (i < 25600) { pack_one(s2, d2, i, 400, 65, 2, 32); return; }
  i -= 25600;
  if (i < 126464) { pack_one(s3, d3, i, 300, 400, 13, -1); return; }
  i -= 126464;
  if (i < 25600) { pack_one(s4, d4, i, 400, 64, 2, -1); return; }
  i -= 25600;
  if (i < 126464) { pack_one(s5, d5, i, 300, 400, 13, -1); return; }
  i -= 126464;
  if (i < 20480) { pack_one(s6, d6, i, 64, 300, 10, -1); return; }
  i -= 20480;
  if (i < 2048) { pack_one(s7, d7, i, 64, 33, 1, -1); return; }   // K=32 cols 0..31
  i -= 2048;
  if (i < 8192) { pack_one(s8, d8, i, 64, 128, 4, -1); return; }
  i -= 8192;
  if (i < 2048) { pack_one(s9, d9, i, 32, 64, 2, -1); return; }
}

// ---------------- bottom-up via MFMA: subtree phase + root phase ----------------
// phase 0: grid (128, 2): blockIdx.y+1 = subtree root (1 or 2); 7-node post-order walk,
//          3 fp32 LDS msg slots. phase 1: grid (128, 1): node 0, children from global.
// Block = 64 rows, 8 waves; wave w -> m-tile (w&3), n-half (w>>2).
__global__ __launch_bounds__(512, 4) void k_up_mfma(
    const float* __restrict__ x, const float* __restrict__ u,
    const unsigned short* __restrict__ w1f, const float* __restrict__ w1raw,  // [64][33]
    const float* __restrict__ b1,
    const unsigned short* __restrict__ w2f, const float* __restrict__ b2,
    const unsigned short* __restrict__ w3f, const float* __restrict__ b3,
    float* __restrict__ msg_up, int phase) {
  __shared__ __align__(16) unsigned short Xs[64 * 40];    // 5120B, K=32 A-tiles
  __shared__ __align__(16) unsigned short Hs[64 * 136];   // 17408B, cols0-63 xu, 64-127 child
  __shared__ __align__(16) unsigned short H2s[64 * 72];   // 9216B
  __shared__ float Ms[3][64][32];                          // 24576B fp32 msg slots
  __shared__ float Red[2][64];                             // 512B
  __shared__ float u_s[64];                                // 256B   total ~57KB
  const int tid = threadIdx.x, w = tid >> 6, l = tid & 63;
  const int lr = l & 15, lh = l >> 4;
  const int mt = w & 3, nh = w >> 2;
  const int r0 = blockIdx.x * 64;
  const int subtree = blockIdx.y + 1;
  const short8* w1v = (const short8*)w1f;
  const short8* w2v = (const short8*)w2f;
  const short8* w3v = (const short8*)w3f;

  const int nsteps = phase ? 1 : 7;
  for (int step = 0; step < nsteps; step++) {
    int node, sl = 0, sr = 0, os = -1;
    bool haveCh;
    if (phase) { node = 0; haveCh = true; }
    else {
      switch (step) {
        case 0: node = 4 * subtree + 3; haveCh = false; os = 0; break;
        case 1: node = 4 * subtree + 4; haveCh = false; os = 1; break;
        case 2: node = 2 * subtree + 1; haveCh = true; sl = 0; sr = 1; os = 2; break;
        case 3: node = 4 * subtree + 5; haveCh = false; os = 0; break;
        case 4: node = 4 * subtree + 6; haveCh = false; os = 1; break;
        case 5: node = 2 * subtree + 2; haveCh = true; sl = 0; sr = 1; os = 0; break;
        default: node = subtree; haveCh = true; sl = 2; sr = 0; os = -1; break;
      }
    }
    const int rbase = (node << LOGB) + r0;

    // ---- stage Xs (x cols as bf16), u, child msgs -> Hs[64..127] (tanh, bf16) ----
    for (int f = tid; f < 64 * 32; f += 512) {
      int r = f >> 5, c = f & 31;
      Xs[r * 40 + c] = f2bf(x[(rbase + r) * 32 + c]);
    }
    if (tid < 64) u_s[tid] = u[rbase + tid];
    if (haveCh) {
      for (int f = tid; f < 64 * 64; f += 512) {
        int r = f >> 6, c = f & 63;
        float v;
        if (phase)
          v = (c < 32) ? msg_up[((1 << LOGB) + r0 + r) * 32 + c]
                       : msg_up[((2 << LOGB) + r0 + r) * 32 + (c - 32)];
        else
          v = (c < 32) ? Ms[sl][r][c] : Ms[sr][r][c - 32];
        Hs[r * 136 + 64 + c] = f2bf(tanh_fast(v));
      }
    }
    __syncthreads();

    // ---- layer 1: X[64x32] @ W1T -> 64 outs; u rank-1; normalize over 64; tanh ----
    f32x4 acc1[2];
#pragma unroll
    for (int t = 0; t < 2; t++) acc1[t] = (f32x4)(0.f);
    {
      short8 a = *(const short8*)&Xs[(mt * 16 + lr) * 40 + lh * 8];
#pragma unroll
      for (int t = 0; t < 2; t++)
        acc1[t] = __builtin_amdgcn_mfma_f32_16x16x32_bf16(a, w1v[(nh * 2 + t) * 64 + l], acc1[t], 0, 0, 0);
    }
    float v1[2][4];
    {
      float vsq[4] = {0.f, 0.f, 0.f, 0.f};
#pragma unroll
      for (int t = 0; t < 2; t++) {
        int n = (nh * 2 + t) * 16 + lr;
        float wu = w1raw[n * 33 + 32];
        float bb = b1[n];
#pragma unroll
        for (int r = 0; r < 4; r++) {
          float vv = acc1[t][r] + u_s[mt * 16 + lh * 4 + r] * wu + bb;
          v1[t][r] = vv;
          vsq[r] += vv * vv;
        }
      }
#pragma unroll
      for (int r = 0; r < 4; r++) {
        float s = vsq[r];
        s += __shfl_xor(s, 1, 64);
        s += __shfl_xor(s, 2, 64);
        s += __shfl_xor(s, 4, 64);
        s += __shfl_xor(s, 8, 64);
        if (lr == 0) Red[nh][mt * 16 + lh * 4 + r] = s;
      }
    }
    __syncthreads();
#pragma unroll
    for (int r = 0; r < 4; r++) {
      int row = mt * 16 + lh * 4 + r;
      float inv = 1.f / fmaxf(sqrtf(Red[0][row] + Red[1][row]), 1e-12f);
#pragma unroll
      for (int t = 0; t < 2; t++)
        Hs[row * 136 + (nh * 2 + t) * 16 + lr] = f2bf(tanh_fast(v1[t][r] * inv));
    }
    __syncthreads();

    // ---- layer 2: H[64x128] @ W2T -> 64; tanh. Leaves: child half zero -> skip ks 2,3 ----
    f32x4 acc2[2];
#pragma unroll
    for (int t = 0; t < 2; t++) acc2[t] = (f32x4)(0.f);
    const int ksmax = haveCh ? 4 : 2;
#pragma unroll
    for (int ks = 0; ks < 4; ks++) {
      if (ks < ksmax) {
        short8 a = *(const short8*)&Hs[(mt * 16 + lr) * 136 + ks * 32 + lh * 8];
#pragma unroll
        for (int t = 0; t < 2; t++)
          acc2[t] = __builtin_amdgcn_mfma_f32_16x16x32_bf16(a, w2v[((nh * 2 + t) * 4 + ks) * 64 + l], acc2[t], 0, 0, 0);
      }
    }
#pragma unroll
    for (int t = 0; t < 2; t++) {
      int n = (nh * 2 + t) * 16 + lr;
      float bb = b2[n];
#pragma unroll
      for (int r = 0; r < 4; r++)
        H2s[(mt * 16 + lh * 4 + r) * 72 + n] = f2bf(tanh_fast(acc2[t][r] + bb));
    }
    __syncthreads();

    // ---- layer 3: H2[64x64] @ W3T -> 32; normalize over 32; write slot+global ----
    f32x4 acc3 = (f32x4)(0.f);
#pragma unroll
    for (int ks = 0; ks < 2; ks++) {
      short8 a = *(const short8*)&H2s[(mt * 16 + lr) * 72 + ks * 32 + lh * 8];
      acc3 = __builtin_amdgcn_mfma_f32_16x16x32_bf16(a, w3v[(nh * 2 + ks) * 64 + l], acc3, 0, 0, 0);
    }
    float v3[4];
    {
      float bb = b3[nh * 16 + lr];
#pragma unroll
      for (int r = 0; r < 4; r++) {
        v3[r] = acc3[r] + bb;
        float s = v3[r] * v3[r];
        s += __shfl_xor(s, 1, 64);
        s += __shfl_xor(s, 2, 64);
        s += __shfl_xor(s, 4, 64);
        s += __shfl_xor(s, 8, 64);
        if (lr == 0) Red[nh][mt * 16 + lh * 4 + r] = s;
      }
    }
    __syncthreads();
    {
      const int n = nh * 16 + lr;
#pragma unroll
      for (int r = 0; r < 4; r++) {
        int row = mt * 16 + lh * 4 + r;
        float inv = 1.f / fmaxf(sqrtf(Red[0][row] + Red[1][row]), 1e-12f);
        float mv = v3[r] * inv;
        msg_up[(rbase + row) * 32 + n] = mv;
        if (os >= 0) Ms[os][row][n] = mv;
      }
    }
    __syncthreads();
  }
}

// ---------------- fused top-down message chain: one kernel walks nodes 0..6 ----------------
__global__ __launch_bounds__(512, 2) void k_mb_fused(
    const float* __restrict__ msg_up,
    const unsigned short* __restrict__ w1f, const unsigned short* __restrict__ w2f,
    const unsigned short* __restrict__ w3f,
    const float* __restrict__ b1, const float* __restrict__ b2, const float* __restrict__ b3,
    float* __restrict__ msg_in_out) {
  __shared__ __align__(16) unsigned short H1s[32 * 424];
  __shared__ __align__(16) unsigned short H2s[32 * 328];
  __shared__ __align__(16) unsigned short MinS[6][32][32];
  __shared__ __align__(16) unsigned char XR[32 * 72 * 2];
  unsigned short* Xs = (unsigned short*)XR;
  float* RedM = (float*)XR;
  const int tid = threadIdx.x;
  const int r0 = blockIdx.x * 32;
  const int w = tid >> 6, l = tid & 63;
  const int lr = l & 15, lh = l >> 4;

  for (int f = tid; f < 32 * 16; f += 512)
    H1s[(f >> 4) * 424 + 400 + (f & 15)] = 0;
  for (int f = tid; f < 32 * 16; f += 512)
    H2s[(f >> 4) * 328 + 304 + (f & 15)] = 0;

  for (int node = 0; node < 7; node++) {
    const int rbase = (node << LOGB) + r0;
    for (int f = tid; f < 32 * 64; f += 512) {
      int r = f >> 6, c = f & 63;
      float v;
      if (c < 32) v = msg_up[(rbase + r) * 32 + c];
      else v = (node > 0) ? bf2f(MinS[node - 1][r][c - 32]) : 0.f;
      Xs[r * 72 + c] = f2bf(tanh_fast(v));
    }
    __syncthreads();

    const int nb1 = (w == 0) ? 0 : (3 * w + 1);
    const int nc1 = (w == 0) ? 4 : 3;
    f32x4 acc1[4][2];
#pragma unroll
    for (int i = 0; i < 4; i++)
#pragma unroll
      for (int m = 0; m < 2; m++) acc1[i][m] = (f32x4)(0.f);
    const short8* w1v = (const short8*)w1f;
#pragma unroll
    for (int ks = 0; ks < 2; ks++) {
      short8 a[2];
#pragma unroll
      for (int m = 0; m < 2; m++)
        a[m] = *(const short8*)&Xs[(m * 16 + lr) * 72 + ks * 32 + lh * 8];
      short8 bfr[4];
#pragma unroll
      for (int nt = 0; nt < 4; nt++)
        if (nt < nc1) bfr[nt] = w1v[((nb1 + nt) * 2 + ks) * 64 + l];
#pragma unroll
      for (int nt = 0; nt < 4; nt++)
        if (nt < nc1)
#pragma unroll
          for (int m = 0; m < 2; m++)
            acc1[nt][m] = __builtin_amdgcn_mfma_f32_16x16x32_bf16(a[m], bfr[nt], acc1[nt][m], 0, 0, 0);
    }
#pragma unroll
    for (int nt = 0; nt < 4; nt++)
      if (nt < nc1) {
        int n = (nb1 + nt) * 16 + lr;
        float bb = b1[n];
#pragma unroll
        for (int m = 0; m < 2; m++)
#pragma unroll
          for (int r = 0; r < 4; r++) {
            float h = fmaxf(acc1[nt][m][r] + bb, 0.f);
            H1s[(m * 16 + lh * 4 + r) * 424 + n] = f2bf(h);
          }
      }
    __syncthreads();

    const int nb2 = (w < 3) ? 3 * w : (9 + 2 * (w - 3));
    const int nc2 = (w < 3) ? 3 : 2;
    f32x4 acc2[3][2];
#pragma unroll
    for (int i = 0; i < 3; i++)
#pragma unroll
      for (int m = 0; m < 2; m++) acc2[i][m] = (f32x4)(0.f);
    const short8* w2v = (const short8*)w2f;
#pragma unroll 2
    for (int ks = 0; ks < 13; ks++) {
      short8 a[2];
#pragma unroll
      for (int m = 0; m < 2; m++)
        a[m] = *(const short8*)&H1s[(m * 16 + lr) * 424 + ks * 32 + lh * 8];
      short8 bfr[3];
#pragma unroll
      for (int nt = 0; nt < 3; nt++)
        if (nt < nc2) bfr[nt] = w2v[((nb2 + nt) * 13 + ks) * 64 + l];
#pragma unroll
      for (int nt = 0; nt < 3; nt++)
        if (nt < nc2)
#pragma unroll
          for (int m = 0; m < 2; m++)
            acc2[nt][m] = __builtin_amdgcn_mfma_f32_16x16x32_bf16(a[m], bfr[nt], acc2[nt][m], 0, 0, 0);
    }
#pragma unroll
    for (int nt = 0; nt < 3; nt++)
      if (nt < nc2) {
        int n = (nb2 + nt) * 16 + lr;
        float bb = (n < 300) ? b2[n] : 0.f;
#pragma unroll
        for (int m = 0; m < 2; m++)
#pragma unroll
          for (int r = 0; r < 4; r++) {
            float h = (n < 300) ? fmaxf(acc2[nt][m][r] + bb, 0.f) : 0.f;
            H2s[(m * 16 + lh * 4 + r) * 328 + n] = f2bf(h);
          }
      }
    __syncthreads();

    f32x4 acc3[2];
#pragma unroll
    for (int m = 0; m < 2; m++) acc3[m] = (f32x4)(0.f);
    float vout[2][4];
    if (w < 4) {
      const short8* w3v = (const short8*)w3f;
#pragma unroll 2
      for (int ks = 0; ks < 10; ks++) {
        short8 a[2];
#pragma unroll
        for (int m = 0; m < 2; m++)
          a[m] = *(const short8*)&H2s[(m * 16 + lr) * 328 + ks * 32 + lh * 8];
        short8 bfr = w3v[(w * 10 + ks) * 64 + l];
#pragma unroll
        for (int m = 0; m < 2; m++)
          acc3[m] = __builtin_amdgcn_mfma_f32_16x16x32_bf16(a[m], bfr, acc3[m], 0, 0, 0);
      }
      float bb = b3[w * 16 + lr];
#pragma unroll
      for (int m = 0; m < 2; m++)
#pragma unroll
        for (int r = 0; r < 4; r++) {
          float v = acc3[m][r] + bb;
          vout[m][r] = v;
          float s = v * v;
          s += __shfl_xor(s, 1, 64);
          s += __shfl_xor(s, 2, 64);
          s += __shfl_xor(s, 4, 64);
          s += __shfl_xor(s, 8, 64);
          if (lr == 0) RedM[w * 32 + m * 16 + lh * 4 + r] = s;
        }
    }
    __syncthreads();
    if (w < 4) {
      const int n3 = w * 16 + lr;
      const int child = 2 * node + 1 + (n3 >> 5);
      const int ccol = n3 & 31;
#pragma unroll
      for (int m = 0; m < 2; m++)
#pragma unroll
        for (int r = 0; r < 4; r++) {
          int row = m * 16 + lh * 4 + r;
          float ss = RedM[0 * 32 + row] + RedM[1 * 32 + row] + RedM[2 * 32 + row] + RedM[3 * 32 + row];
          float inv = 1.f / fmaxf(sqrtf(ss), 1e-12f);
          float mv = vout[m][r] * inv;
          msg_in_out[((child << LOGB) + r0 + row) * 32 + ccol] = mv;
          if (child <= 6) MinS[child - 1][row][ccol] = f2bf(mv);
        }
    }
    __syncthreads();
  }
}

// ---------------- Q nets via MFMA: 512 threads, 64 rows/block, ALL 15 nodes, q1/q2 via blockIdx.y ----
__global__ __launch_bounds__(512, 4) void k_q_mfma(
    const float* __restrict__ msg_up, const float* __restrict__ u,
    const float* __restrict__ msg_in,
    const unsigned short* __restrict__ w1fA, const unsigned short* __restrict__ w2fA,
    const float* __restrict__ w1oA, const float* __restrict__ b1A,
    const float* __restrict__ b2A, const float* __restrict__ w3A, const float* __restrict__ b3A,
    const unsigned short* __restrict__ w1fB, const unsigned short* __restrict__ w2fB,
    const float* __restrict__ w1oB, const float* __restrict__ b1B,
    const float* __restrict__ b2B, const float* __restrict__ w3B, const float* __restrict__ b3B,
    float* __restrict__ out) {
  __shared__ __align__(16) unsigned char sraw[64 * 72 * 2];
  __shared__ __align__(16) unsigned short H1s[64 * 424];
  __shared__ float u_s[64];
  unsigned short* Xs = (unsigned short*)sraw;
  float* Red = (float*)sraw;

  const int tid = threadIdx.x;
  const int net = blockIdx.y;
  const unsigned short* w1f = net ? w1fB : w1fA;
  const unsigned short* w2f = net ? w2fB : w2fA;
  const float* w1o = net ? w1oB : w1oA;
  const float* b1 = net ? b1B : b1A;
  const float* b2 = net ? b2B : b2A;
  const float* w3 = net ? w3B : w3A;
  const float* b3 = net ? b3B : b3A;
  const int r0 = blockIdx.x * 64;
  const int node = r0 >> LOGB;
  const int has_parent = (node > 0);

  for (int f = tid; f < 64 * 64; f += 512) {
    int r = f >> 6, c = f & 63;
    int row = r0 + r;
    float v = (c < 32) ? msg_up[row * 32 + c]
                       : (has_parent ? msg_in[row * 32 + (c - 32)] : 0.f);
    Xs[r * 72 + c] = f2bf(v);
  }
  for (int f = tid; f < 64 * 16; f += 512)
    H1s[(f >> 4) * 424 + 400 + (f & 15)] = 0;
  if (tid < 64) u_s[tid] = u[r0 + tid];
  __syncthreads();

  const int w = tid >> 6, l = tid & 63;
  const int lr = l & 15, lh = l >> 4;

  const int nb1 = (w == 0) ? 0 : (3 * w + 1);
  const int nc1 = (w == 0) ? 4 : 3;
  f32x4 acc1[4][4];
#pragma unroll
  for (int i = 0; i < 4; i++)
#pragma unroll
    for (int m = 0; m < 4; m++) acc1[i][m] = (f32x4)(0.f);
  const short8* w1v = (const short8*)w1f;
#pragma unroll
  for (int ks = 0; ks < 2; ks++) {
    short8 a[4];
#pragma unroll
    for (int m = 0; m < 4; m++)
      a[m] = *(const short8*)&Xs[(m * 16 + lr) * 72 + ks * 32 + lh * 8];
    short8 bfr[4];
#pragma unroll
    for (int nt = 0; nt < 4; nt++)
      if (nt < nc1) bfr[nt] = w1v[((nb1 + nt) * 2 + ks) * 64 + l];
#pragma unroll
    for (int nt = 0; nt < 4; nt++)
      if (nt < nc1)
#pragma unroll
        for (int m = 0; m < 4; m++)
          acc1[nt][m] = __builtin_amdgcn_mfma_f32_16x16x32_bf16(a[m], bfr[nt], acc1[nt][m], 0, 0, 0);
  }
  float uv[4][4];
#pragma unroll
  for (int m = 0; m < 4; m++)
#pragma unroll
    for (int r = 0; r < 4; r++) uv[m][r] = u_s[m * 16 + lh * 4 + r];
#pragma unroll
  for (int nt = 0; nt < 4; nt++)
    if (nt < nc1) {
      int n = (nb1 + nt) * 16 + lr;
      float wu = w1o[n * 65 + 32];
      float bb = b1[n];
#pragma unroll
      for (int m = 0; m < 4; m++)
#pragma unroll
        for (int r = 0; r < 4; r++) {
          float h = acc1[nt][m][r] + uv[m][r] * wu + bb;
          h = fmaxf(h, 0.f);
          H1s[(m * 16 + lh * 4 + r) * 424 + n] = f2bf(h);
        }
    }
  __syncthreads();

  const int nb2 = (w < 3) ? 3 * w : (9 + 2 * (w - 3));
  const int nc2 = (w < 3) ? 3 : 2;
  f32x4 acc2[3][4];
#pragma unroll
  for (int i = 0; i < 3; i++)
#pragma unroll
    for (int m = 0; m < 4; m++) acc2[i][m] = (f32x4)(0.f);
  const short8* w2v = (const short8*)w2f;
#pragma unroll 2
  for (int ks = 0; ks < 13; ks++) {
    short8 a[4];
#pragma unroll
    for (int m = 0; m < 4; m++)
      a[m] = *(const short8*)&H1s[(m * 16 + lr) * 424 + ks * 32 + lh * 8];
    short8 bfr[3];
#pragma unroll
    for (int nt = 0; nt < 3; nt++)
      if (nt < nc2) bfr[nt] = w2v[((nb2 + nt) * 13 + ks) * 64 + l];
#pragma unroll
    for (int nt = 0; nt < 3; nt++)
      if (nt < nc2)
#pragma unroll
        for (int m = 0; m < 4; m++)
          acc2[nt][m] = __builtin_amdgcn_mfma_f32_16x16x32_bf16(a[m], bfr[nt], acc2[nt][m], 0, 0, 0);
  }
  float part[4][4];
#pragma unroll
  for (int m = 0; m < 4; m++)
#pragma unroll
    for (int r = 0; r < 4; r++) part[m][r] = 0.f;
#pragma unroll
  for (int nt = 0; nt < 3; nt++)
    if (nt < nc2) {
      int n = (nb2 + nt) * 16 + lr;
      float bb = (n < 300) ? b2[n] : 0.f;
      float w3n = (n < 300) ? w3[n] : 0.f;
#pragma unroll
      for (int m = 0; m < 4; m++)
#pragma unroll
        for (int r = 0; r < 4; r++) {
          float h = fmaxf(acc2[nt][m][r] + bb, 0.f);
          part[m][r] = fmaf(h, w3n, part[m][r]);
        }
    }
#pragma unroll
  for (int m = 0; m < 4; m++)
#pragma unroll
    for (int r = 0; r < 4; r++) {
      float p = part[m][r];
      p += __shfl_xor(p, 1, 64);
      p += __shfl_xor(p, 2, 64);
      p += __shfl_xor(p, 4, 64);
      p += __shfl_xor(p, 8, 64);
      if (lr == 0) Red[w * 64 + m * 16 + lh * 4 + r] = p;
    }
  __syncthreads();
  if (tid < 64) {
    float q = b3[0];
#pragma unroll
    for (int i = 0; i < 8; i++) q += Red[i * 64 + tid];
    out[(r0 + tid) * 2 + net] = q;
  }
}

extern "C" void kernel_launch(void* const* d_in, const int* in_sizes, int n_in,
                              void* d_out, int out_size, void* d_ws, size_t ws_size,
                              hipStream_t stream) {
  const float* x    = (const float*)d_in[0];
  const float* u    = (const float*)d_in[1];
  const float* up1w = (const float*)d_in[2];  const float* up1b = (const float*)d_in[3];
  const float* up2w = (const float*)d_in[4];  const float* up2b = (const float*)d_in[5];
  const float* up3w = (const float*)d_in[6];  const float* up3b = (const float*)d_in[7];
  const float* q1w1 = (const float*)d_in[8];  const float* q1b1 = (const float*)d_in[9];
  const float* q1w2 = (const float*)d_in[10]; const float* q1b2 = (const float*)d_in[11];
  const float* q1w3 = (const float*)d_in[12]; const float* q1b3 = (const float*)d_in[13];
  const float* q2w1 = (const float*)d_in[14]; const float* q2b1 = (const float*)d_in[15];
  const float* q2w2 = (const float*)d_in[16]; const float* q2b2 = (const float*)d_in[17];
  const float* q2w3 = (const float*)d_in[18]; const float* q2b3 = (const float*)d_in[19];
  const float* mbw1 = (const float*)d_in[20]; const float* mbb1 = (const float*)d_in[21];
  const float* mbw2 = (const float*)d_in[22]; const float* mbb2 = (const float*)d_in[23];
  const float* mbw3 = (const float*)d_in[24]; const float* mbb3 = (const float*)d_in[25];
  float* out = (float*)d_out;
  float* ws  = (float*)d_ws;

  float* msg_up = ws;                        // 15*8192*32
  float* msg_in = msg_up + 15 * BN * 32;     // 15*8192*32
  unsigned short* frag = (unsigned short*)(msg_in + 15 * BN * 32);
  unsigned short* q1w1f = frag;              // 25600
  unsigned short* q1w2f = q1w1f + 25600;     // 126464
  unsigned short* q2w1f = q1w2f + 126464;
  unsigned short* q2w2f = q2w1f + 25600;
  unsigned short* mbw1f = q2w2f + 126464;
  unsigned short* mbw2f = mbw1f + 25600;
  unsigned short* mbw3f = mbw2f + 126464;    // 20480
  unsigned short* up1f  = mbw3f + 20480;     // 2048
  unsigned short* up2f  = up1f + 2048;       // 8192
  unsigned short* up3f  = up2f + 8192;       // 2048

  k_prep_pack<<<dim3((488960 + 255) / 256), dim3(256), 0, stream>>>(
      q1w1, q1w1f, q1w2, q1w2f, q2w1, q2w1f, q2w2, q2w2f,
      mbw1, mbw1f, mbw2, mbw2f, mbw3, mbw3f,
      up1w, up1f, up2w, up2f, up3w, up3f);

  // ---- bottom-up via MFMA: subtree phase (2 independent subtrees), then root ----
  k_up_mfma<<<dim3(BN / 64, 2), dim3(512), 0, stream>>>(
      x, u, up1f, up1w, up1b, up2f, up2b, up3f, up3b, msg_up, 0);
  k_up_mfma<<<dim3(BN / 64, 1), dim3(512), 0, stream>>>(
      x, u, up1f, up1w, up1b, up2f, up2b, up3f, up3b, msg_up, 1);

  // ---- fused message chain: one launch ----
  k_mb_fused<<<dim3(BN / 32), dim3(512), 0, stream>>>(
      msg_up, mbw1f, mbw2f, mbw3f, mbb1, mbb2, mbb3, msg_in);

  // ---- Q: one launch over all 15 nodes, both nets ----
  k_q_mfma<<<dim3(15 * (BN / 64), 2), dim3(512), 0, stream>>>(
      msg_up, u, msg_in,
      q1w1f, q1w2f, q1w1, q1b1, q1b2, q1w3, q1b3,
      q2w1f, q2w2f, q2w1, q2b1, q2b2, q2w3, q2b3,
      out);
}